// Round 1
// baseline (1295.520 us; speedup 1.0000x reference)
//
#include <hip/hip_runtime.h>
#include <stdint.h>

typedef unsigned short u16;
typedef unsigned int u32;
typedef short bf16x8 __attribute__((ext_vector_type(8)));
typedef float f32x4 __attribute__((ext_vector_type(4)));

#define DEV __device__ __forceinline__

DEV float bf2f(u16 u) { union { float f; u32 i; } x; x.i = ((u32)u) << 16; return x.f; }
DEV u16 f2bf(float f) {
  union { float f; u32 i; } x; x.f = f;
  u32 i = x.i;
  u32 r = (i + 0x7fffu + ((i >> 16) & 1u)) >> 16;  // RTNE
  return (u16)r;
}

// async global->LDS, 16B per lane. lds base must be wave-uniform; HW adds lane*16.
DEV void gl_lds16(const u16* g, u16* l) {
  __builtin_amdgcn_global_load_lds((const __attribute__((address_space(1))) u32*)g,
                                   (__attribute__((address_space(3))) u32*)l, 16, 0, 0);
}

// ---------------- cast fp32 -> bf16 (vectorized) ----------------
typedef u16 u16x4 __attribute__((ext_vector_type(4)));
__global__ __launch_bounds__(256) void cast_f32_bf16(const float* __restrict__ in,
                                                     u16* __restrict__ out, int n4) {
  int i = blockIdx.x * 256 + threadIdx.x;
  if (i >= n4) return;
  float4 v = ((const float4*)in)[i];
  u16x4 o;
  o.x = f2bf(v.x); o.y = f2bf(v.y); o.z = f2bf(v.z); o.w = f2bf(v.w);
  ((u16x4*)out)[i] = o;
}

// ---------------- transpose + cast: W (K,N) fp32 -> Wt (N,K) bf16 ----------------
__global__ __launch_bounds__(256) void transpose_cast(const float* __restrict__ W,
                                                      u16* __restrict__ Wt, int K, int N) {
  __shared__ float tile[64][65];
  int n0 = blockIdx.x * 64;
  int k0 = blockIdx.y * 64;
#pragma unroll
  for (int i = 0; i < 16; ++i) {
    int idx = threadIdx.x + i * 256;
    int r = idx >> 6, c = idx & 63;             // r: k-off, c: n-off
    tile[r][c] = W[(size_t)(k0 + r) * N + n0 + c];
  }
  __syncthreads();
#pragma unroll
  for (int i = 0; i < 16; ++i) {
    int idx = threadIdx.x + i * 256;
    int r = idx >> 6, c = idx & 63;             // r: n-off, c: k-off
    Wt[(size_t)(n0 + r) * K + k0 + c] = f2bf(tile[c][r]);
  }
}

// ---------------- transpose V: (B*L, 2048) bf16, cols h*128+dv -> Vt (B,H,128,L) ----------------
__global__ __launch_bounds__(256) void transpose_v(const u16* __restrict__ V,
                                                   u16* __restrict__ Vt) {
  __shared__ float tile[64][65];
  int l0 = blockIdx.x * 64;   // 32 tiles over L
  int d0 = blockIdx.y * 64;   // 2 tiles over 128
  int bh = blockIdx.z;        // b*16+h
  int b = bh >> 4, h = bh & 15;
#pragma unroll
  for (int i = 0; i < 16; ++i) {
    int idx = threadIdx.x + i * 256;
    int r = idx >> 6, c = idx & 63;
    tile[r][c] = bf2f(V[(size_t)(b * 2048 + l0 + r) * 2048 + h * 128 + d0 + c]);
  }
  __syncthreads();
#pragma unroll
  for (int i = 0; i < 16; ++i) {
    int idx = threadIdx.x + i * 256;
    int rr = idx >> 6, cc = idx & 63;  // rr: dv-off, cc: l-off
    Vt[((size_t)bh * 128 + d0 + rr) * 2048 + l0 + cc] = f2bf(tile[cc][rr]);
  }
}

// ---------------- GEMM: C(MxN) = A(MxK bf16) * Bt(NxK bf16)^T, m97 structure ----------------
DEV void gemm_store(float* C, size_t idx, float v) { C[idx] = v; }
DEV void gemm_store(u16* C, size_t idx, float v) { C[idx] = f2bf(v); }

template <typename OT>
__global__ __launch_bounds__(256) void gemm_bt(const u16* __restrict__ A,
                                               const u16* __restrict__ Bt,
                                               OT* __restrict__ C, int M, int N, int K) {
  __shared__ u16 As[128 * 32];
  __shared__ u16 Bs[128 * 32];
  const int tid = threadIdx.x;
  const int lane = tid & 63;
  const int w = tid >> 6;       // 0..3
  const int quad = lane >> 4;   // 0..3
  const int l15 = lane & 15;
  const int m0 = blockIdx.y * 128;
  const int n0 = blockIdx.x * 128;
  const int wm = (w & 1) * 64;
  const int wn = (w >> 1) * 64;

  f32x4 acc[4][4] = {};

  for (int k0 = 0; k0 < K; k0 += 32) {
    // stage A and B tiles: 512 16B-chunks each; wave w covers chunks [w*128, w*128+128)
#pragma unroll
    for (int it = 0; it < 2; ++it) {
      int ca = w * 128 + it * 64;       // wave-uniform base chunk
      int c = ca + lane;
      int row = c >> 2, kc = (c & 3) * 8;
      gl_lds16(A + (size_t)(m0 + row) * K + k0 + kc, &As[ca * 8]);
      gl_lds16(Bt + (size_t)(n0 + row) * K + k0 + kc, &Bs[ca * 8]);
    }
    __syncthreads();   // waits vmcnt(0) for global_load_lds
    bf16x8 af[4], bf[4];
#pragma unroll
    for (int mt = 0; mt < 4; ++mt) af[mt] = *(const bf16x8*)&As[(wm + mt * 16 + l15) * 32 + quad * 8];
#pragma unroll
    for (int nt = 0; nt < 4; ++nt) bf[nt] = *(const bf16x8*)&Bs[(wn + nt * 16 + l15) * 32 + quad * 8];
#pragma unroll
    for (int mt = 0; mt < 4; ++mt)
#pragma unroll
      for (int nt = 0; nt < 4; ++nt)
        acc[mt][nt] = __builtin_amdgcn_mfma_f32_16x16x32_bf16(af[mt], bf[nt], acc[mt][nt], 0, 0, 0);
    __syncthreads();
  }
  // epilogue: D row = quad*4+r, col = l15 (verified m89/m91 layout)
#pragma unroll
  for (int mt = 0; mt < 4; ++mt)
#pragma unroll
    for (int nt = 0; nt < 4; ++nt) {
      int col = n0 + wn + nt * 16 + l15;
      if (col >= N) continue;   // only triggers for N=64 (W_KR)
#pragma unroll
      for (int r = 0; r < 4; ++r) {
        int rowg = m0 + wm + mt * 16 + quad * 4 + r;
        gemm_store(C, (size_t)rowg * N + col, acc[mt][nt][r]);
      }
    }
}

// ---------------- build q / k: rope + concat + L2-normalize, one wave per (token, head) ----------------
__global__ __launch_bounds__(256) void build_q(const u16* __restrict__ qc,
                                               const u16* __restrict__ qrr,
                                               const float* __restrict__ s_qk,
                                               u16* __restrict__ qn) {
  const int wid = blockIdx.x * 4 + (threadIdx.x >> 6);
  const int lane = threadIdx.x & 63;
  const int token = wid >> 4;     // b*L + l
  const int h = wid & 15;
  const int b = token >> 11;
  const int l = token & 2047;
  float v0 = bf2f(qc[(size_t)token * 2048 + h * 128 + lane]);
  float v1 = bf2f(qc[(size_t)token * 2048 + h * 128 + 64 + lane]);
  int j = lane & 31;
  float freq = powf(10000.f, -(float)j * (1.f / 32.f));
  float ang = (float)l * freq;
  float cs = cosf(ang), sn = sinf(ang);
  float xr = bf2f(qrr[(size_t)token * 1024 + h * 64 + lane]);
  float xo = bf2f(qrr[(size_t)token * 1024 + h * 64 + (lane ^ 32)]);
  float v2 = (lane < 32) ? (xr * cs - xo * sn) : (xr * cs + xo * sn);
  float ss = v0 * v0 + v1 * v1 + v2 * v2;
#pragma unroll
  for (int off = 1; off < 64; off <<= 1) ss += __shfl_xor(ss, off, 64);
  float scale = s_qk[0] / fmaxf(sqrtf(ss), 1e-12f);
  u16* out = qn + (((size_t)(b * 16 + h) * 2048) + l) * 192;
  out[lane] = f2bf(v0 * scale);
  out[64 + lane] = f2bf(v1 * scale);
  out[128 + lane] = f2bf(v2 * scale);
}

__global__ __launch_bounds__(256) void build_k(const u16* __restrict__ kc_,
                                               const u16* __restrict__ krr,
                                               u16* __restrict__ kn) {
  const int wid = blockIdx.x * 4 + (threadIdx.x >> 6);
  const int lane = threadIdx.x & 63;
  const int token = wid >> 4;
  const int h = wid & 15;
  const int b = token >> 11;
  const int l = token & 2047;
  float v0 = bf2f(kc_[(size_t)token * 2048 + h * 128 + lane]);
  float v1 = bf2f(kc_[(size_t)token * 2048 + h * 128 + 64 + lane]);
  int j = lane & 31;
  float freq = powf(10000.f, -(float)j * (1.f / 32.f));
  float ang = (float)l * freq;
  float cs = cosf(ang), sn = sinf(ang);
  float xr = bf2f(krr[(size_t)token * 64 + lane]);
  float xo = bf2f(krr[(size_t)token * 64 + (lane ^ 32)]);
  float v2 = (lane < 32) ? (xr * cs - xo * sn) : (xr * cs + xo * sn);
  float ss = v0 * v0 + v1 * v1 + v2 * v2;
#pragma unroll
  for (int off = 1; off < 64; off <<= 1) ss += __shfl_xor(ss, off, 64);
  float scale = 1.0f / fmaxf(sqrtf(ss), 1e-12f);
  u16* out = kn + (((size_t)(b * 16 + h) * 2048) + l) * 192;
  out[lane] = f2bf(v0 * scale);
  out[64 + lane] = f2bf(v1 * scale);
  out[128 + lane] = f2bf(v2 * scale);
}

// ---------------- flash attention (causal), 512 thr, Q in regs, 64-key KV tiles ----------------
__global__ __launch_bounds__(512) void flash_attn(const u16* __restrict__ Q,   // (B,H,L,192)
                                                  const u16* __restrict__ Kn,  // (B,H,L,192)
                                                  const u16* __restrict__ Vt,  // (B,H,128,L)
                                                  u16* __restrict__ O) {       // (B,L,2048)
  constexpr int L = 2048, DQK = 192, DV = 128;
  __shared__ u16 Ks[64 * 200];       // key rows, padded 192->200 (conflict-free frags)
  __shared__ u16 Vs[128 * 72];       // dv rows x 64 keys, padded 64->72
  __shared__ u16 Ps[8 * 16 * 72];    // wave-private P staging, padded
  const int tid = threadIdx.x;
  const int lane = tid & 63;
  const int w = tid >> 6;       // 0..7, q-row group
  const int quad = lane >> 4;
  const int l15 = lane & 15;
  const int qt = blockIdx.x;    // 0..15
  const int bh = blockIdx.y;    // 0..63
  const int b = bh >> 4, h = bh & 15;

  const u16* Qg = Q + ((size_t)bh * L + qt * 128) * DQK;
  const u16* Kg = Kn + (size_t)bh * L * DQK;
  const u16* Vg = Vt + (size_t)bh * DV * L;

  // Q fragments in registers: wave w owns q rows w*16..w*16+15
  bf16x8 qf[6];
#pragma unroll
  for (int kd = 0; kd < 6; ++kd)
    qf[kd] = *(const bf16x8*)&Qg[(w * 16 + l15) * DQK + kd * 32 + quad * 8];

  f32x4 oacc[8] = {};
  float mrow[4], lrow[4];
#pragma unroll
  for (int r = 0; r < 4; ++r) { mrow[r] = -1e30f; lrow[r] = 0.f; }

  const int nkv = 2 * qt + 2;
  for (int kt = 0; kt < nkv; ++kt) {
    // stage K tile: 64 rows x 24 chunks = 1536 / 512 thr = 3 each
#pragma unroll
    for (int i = 0; i < 3; ++i) {
      int c = tid + i * 512;
      int r = c / 24, kc = (c % 24) * 8;
      *(uint4*)&Ks[r * 200 + kc] = *(const uint4*)&Kg[(size_t)(kt * 64 + r) * DQK + kc];
    }
    // stage V tile (already dv-major): 128 x 8 chunks = 1024 / 512 = 2 each
#pragma unroll
    for (int i = 0; i < 2; ++i) {
      int c = tid + i * 512;
      int dv = c >> 3, kc = (c & 7) * 8;
      *(uint4*)&Vs[dv * 72 + kc] = *(const uint4*)&Vg[(size_t)dv * L + kt * 64 + kc];
    }
    __syncthreads();

    // S (16q x 64k) per wave
    f32x4 s[4] = {};
#pragma unroll
    for (int kd = 0; kd < 6; ++kd) {
      bf16x8 a = qf[kd];
#pragma unroll
      for (int nt = 0; nt < 4; ++nt) {
        bf16x8 bb = *(const bf16x8*)&Ks[(nt * 16 + l15) * 200 + kd * 32 + quad * 8];
        s[nt] = __builtin_amdgcn_mfma_f32_16x16x32_bf16(a, bb, s[nt], 0, 0, 0);
      }
    }

    // causal mask + online softmax (rows quad*4+r, cols l15+16*nt)
    const int qrow_base = qt * 128 + w * 16 + quad * 4;
    const int kcol = kt * 64 + l15;
    float pv[4][4];  // [nt][r]
#pragma unroll
    for (int r = 0; r < 4; ++r) {
      float mx = -1e30f;
#pragma unroll
      for (int nt = 0; nt < 4; ++nt) {
        float sv = s[nt][r];
        if (kcol + nt * 16 > qrow_base + r) sv = -1e30f;
        s[nt][r] = sv;
        mx = fmaxf(mx, sv);
      }
#pragma unroll
      for (int off = 1; off < 16; off <<= 1) mx = fmaxf(mx, __shfl_xor(mx, off, 64));
      float mnew = fmaxf(mrow[r], mx);
      float alpha = __expf(mrow[r] - mnew);
      float rs = 0.f;
#pragma unroll
      for (int nt = 0; nt < 4; ++nt) {
        float p = __expf(s[nt][r] - mnew);
        pv[nt][r] = p;
        rs += p;
      }
#pragma unroll
      for (int off = 1; off < 16; off <<= 1) rs += __shfl_xor(rs, off, 64);
      lrow[r] = lrow[r] * alpha + rs;
      mrow[r] = mnew;
#pragma unroll
      for (int nt2 = 0; nt2 < 8; ++nt2) oacc[nt2][r] *= alpha;
    }

    // P -> LDS (C-layout scatter), then read back in A-layout (wave-private region)
    u16* Pw = &Ps[w * 16 * 72];
#pragma unroll
    for (int nt = 0; nt < 4; ++nt)
#pragma unroll
      for (int r = 0; r < 4; ++r)
        Pw[(quad * 4 + r) * 72 + nt * 16 + l15] = f2bf(pv[nt][r]);
    asm volatile("s_waitcnt lgkmcnt(0)" ::: "memory");  // within-wave LDS WAR->RAW order

    // O += P * V
#pragma unroll
    for (int kk = 0; kk < 2; ++kk) {
      bf16x8 p = *(const bf16x8*)&Pw[l15 * 72 + kk * 32 + quad * 8];
#pragma unroll
      for (int nt2 = 0; nt2 < 8; ++nt2) {
        bf16x8 vv = *(const bf16x8*)&Vs[(nt2 * 16 + l15) * 72 + kk * 32 + quad * 8];
        oacc[nt2] = __builtin_amdgcn_mfma_f32_16x16x32_bf16(p, vv, oacc[nt2], 0, 0, 0);
      }
    }
    __syncthreads();  // before restaging Ks/Vs
  }

  // final: divide by l, store O (B,L,2048) bf16
#pragma unroll
  for (int nt2 = 0; nt2 < 8; ++nt2)
#pragma unroll
    for (int r = 0; r < 4; ++r) {
      int lg = qt * 128 + w * 16 + quad * 4 + r;
      float ov = oacc[nt2][r] / lrow[r];
      O[((size_t)b * L + lg) * 2048 + h * 128 + nt2 * 16 + l15] = f2bf(ov);
    }
}

// ---------------- launcher ----------------
extern "C" void kernel_launch(void* const* d_in, const int* in_sizes, int n_in,
                              void* d_out, int out_size, void* d_ws, size_t ws_size,
                              hipStream_t stream) {
  const float* x     = (const float*)d_in[0];
  const float* W_DKV = (const float*)d_in[1];
  const float* W_UK  = (const float*)d_in[2];
  const float* W_UV  = (const float*)d_in[3];
  const float* W_DQ  = (const float*)d_in[4];
  const float* W_UQ  = (const float*)d_in[5];
  const float* W_QR  = (const float*)d_in[6];
  const float* W_KR  = (const float*)d_in[7];
  const float* W_O   = (const float*)d_in[8];
  const float* s_qk  = (const float*)d_in[9];

  char* p = (char*)d_ws;
  auto alloc = [&](size_t bytes) {
    char* r = p;
    p += (bytes + 255) & ~(size_t)255;
    return r;
  };
  u16* xb    = (u16*)alloc((size_t)8192 * 2048 * 2);   // region start (later reused by qn)
  u16* WtDKV = (u16*)alloc((size_t)1024 * 2048 * 2);
  u16* WtUK  = (u16*)alloc((size_t)2048 * 1024 * 2);
  u16* WtUV  = (u16*)alloc((size_t)2048 * 1024 * 2);
  u16* WtDQ  = (u16*)alloc((size_t)1024 * 2048 * 2);
  u16* WtUQ  = (u16*)alloc((size_t)2048 * 1024 * 2);
  u16* WtQR  = (u16*)alloc((size_t)1024 * 1024 * 2);
  u16* WtKR  = (u16*)alloc((size_t)128 * 2048 * 2);    // padded 64->128 rows (GEMM over-read)
  u16* WtO   = (u16*)alloc((size_t)2048 * 2048 * 2);
  u16* ckv   = (u16*)alloc((size_t)8192 * 1024 * 2);
  u16* cq    = (u16*)alloc((size_t)8192 * 1024 * 2);
  u16* kc    = (u16*)alloc((size_t)8192 * 2048 * 2);   // later reused as Vt
  u16* vb    = (u16*)alloc((size_t)8192 * 2048 * 2);
  u16* qc    = (u16*)alloc((size_t)8192 * 2048 * 2);   // later reused as O
  u16* qr    = (u16*)alloc((size_t)8192 * 1024 * 2);
  u16* kr    = (u16*)alloc((size_t)8192 * 64 * 2);
  u16* kn    = (u16*)alloc((size_t)64 * 2048 * 192 * 2);
  // aliases (all writers run strictly after the aliased buffer's last reader):
  u16* qn = (u16*)d_ws;  // 50,331,648 B == xb+WtDKV+WtUK+WtUV+WtDQ exactly; all dead before build_q
  u16* Vt = kc;          // kc dead after build_k
  u16* O  = qc;          // qc dead after build_q

  // 1) casts / weight transposes
  cast_f32_bf16<<<16384, 256, 0, stream>>>(x, xb, 8192 * 2048 / 4);
  transpose_cast<<<dim3(16, 32), 256, 0, stream>>>(W_DKV, WtDKV, 2048, 1024);
  transpose_cast<<<dim3(32, 16), 256, 0, stream>>>(W_UK,  WtUK,  1024, 2048);
  transpose_cast<<<dim3(32, 16), 256, 0, stream>>>(W_UV,  WtUV,  1024, 2048);
  transpose_cast<<<dim3(16, 32), 256, 0, stream>>>(W_DQ,  WtDQ,  2048, 1024);
  transpose_cast<<<dim3(32, 16), 256, 0, stream>>>(W_UQ,  WtUQ,  1024, 2048);
  transpose_cast<<<dim3(16, 16), 256, 0, stream>>>(W_QR,  WtQR,  1024, 1024);
  transpose_cast<<<dim3(1, 32),  256, 0, stream>>>(W_KR,  WtKR,  2048, 64);
  transpose_cast<<<dim3(32, 32), 256, 0, stream>>>(W_O,   WtO,   2048, 2048);

  // 2) projection GEMMs
  gemm_bt<u16><<<dim3(8, 64),  256, 0, stream>>>(xb,  WtDKV, ckv, 8192, 1024, 2048);
  gemm_bt<u16><<<dim3(8, 64),  256, 0, stream>>>(xb,  WtDQ,  cq,  8192, 1024, 2048);
  gemm_bt<u16><<<dim3(16, 64), 256, 0, stream>>>(ckv, WtUK,  kc,  8192, 2048, 1024);
  gemm_bt<u16><<<dim3(16, 64), 256, 0, stream>>>(ckv, WtUV,  vb,  8192, 2048, 1024);
  gemm_bt<u16><<<dim3(16, 64), 256, 0, stream>>>(cq,  WtUQ,  qc,  8192, 2048, 1024);
  gemm_bt<u16><<<dim3(8, 64),  256, 0, stream>>>(cq,  WtQR,  qr,  8192, 1024, 1024);
  gemm_bt<u16><<<dim3(1, 64),  256, 0, stream>>>(xb,  WtKR,  kr,  8192, 64,   2048);

  // 3) rope + concat + normalize
  build_q<<<32768, 256, 0, stream>>>(qc, qr, s_qk, qn);
  build_k<<<32768, 256, 0, stream>>>(kc, kr, kn);

  // 4) V transpose (writes over kc region — kc consumed above)
  transpose_v<<<dim3(32, 2, 64), 256, 0, stream>>>(vb, Vt);

  // 5) attention (writes over qc region — qc consumed above)
  flash_attn<<<dim3(16, 64), 512, 0, stream>>>(qn, kn, Vt, O);

  // 6) output projection -> fp32 d_out
  gemm_bt<float><<<dim3(16, 64), 256, 0, stream>>>(O, WtO, (float*)d_out, 8192, 2048, 2048);
}